// Round 7
// baseline (838.747 us; speedup 1.0000x reference)
//
#include <hip/hip_runtime.h>
#include <hip/hip_bf16.h>
#include <hip/hip_fp16.h>
#include <math.h>

#define NFEAT 128
#define NCLS  64
#define RQ    16            // uint4 per fp16 row (128*2/16)
#define WSTR  132           // W LDS row stride in halves (264 B, b64-aligned, conflict-light)

// ---------- helpers ----------

__device__ __forceinline__ void accum_h8(float acc[8], uint4 v) {
    union { uint4 u; __half2 h[4]; } c; c.u = v;
    #pragma unroll
    for (int t = 0; t < 4; ++t) {
        float2 f = __half22float2(c.h[t]);
        acc[2 * t]     += f.x;
        acc[2 * t + 1] += f.y;
    }
}

typedef _Float16 h2v __attribute__((ext_vector_type(2)));

__device__ __forceinline__ float dot2acc(unsigned int hv, unsigned int wv, float c) {
#if __has_builtin(__builtin_amdgcn_fdot2)
    union { unsigned int u; h2v v; } a, bq; a.u = hv; bq.u = wv;
    return __builtin_amdgcn_fdot2(a.v, bq.v, c, false);
#else
    union { unsigned int u; __half2 h; } a, bq; a.u = hv; bq.u = wv;
    float2 fa = __half22float2(a.h), fb = __half22float2(bq.h);
    return fmaf(fa.x, fb.x, fmaf(fa.y, fb.y, c));
#endif
}

// ---------- graph build ----------

__global__ void count_kernel(const int* __restrict__ dst, int* __restrict__ cnt, int E) {
    int e4 = blockIdx.x * blockDim.x + threadIdx.x;     // 4 edges per thread
    if (e4 * 4 + 3 < E) {
        int4 d = ((const int4*)dst)[e4];
        atomicAdd(&cnt[d.x], 1); atomicAdd(&cnt[d.y], 1);
        atomicAdd(&cnt[d.z], 1); atomicAdd(&cnt[d.w], 1);
    } else {
        for (int e = e4 * 4; e < E; ++e) atomicAdd(&cnt[dst[e]], 1);
    }
}

// scan over PADDED counts (round up to multiple of 4)
__global__ void scan_local(const int* __restrict__ cnt, int* __restrict__ row_ptr,
                           int* __restrict__ bsums, int n) {
    __shared__ int lds[256];
    const int tid = threadIdx.x;
    int i = blockIdx.x * 256 + tid;
    int v = (i < n) ? ((cnt[i] + 3) & ~3) : 0;
    lds[tid] = v;
    __syncthreads();
    for (int off = 1; off < 256; off <<= 1) {
        int t = (tid >= off) ? lds[tid - off] : 0;
        __syncthreads();
        lds[tid] += t;
        __syncthreads();
    }
    if (i < n) row_ptr[i + 1] = lds[tid];
    if (tid == 255) bsums[blockIdx.x] = lds[255];
}

// finalize + degree histogram for load-balancing permutation
__global__ void scan_finalize(const int* __restrict__ cnt, const int* __restrict__ bsums,
                              int* __restrict__ row_ptr, int* __restrict__ cursor,
                              float* __restrict__ dinv, int* __restrict__ hist, int n) {
    __shared__ int wsum[4];
    const int tid = threadIdx.x;
    int v = (tid < blockIdx.x) ? bsums[tid] : 0;
    for (int o = 32; o > 0; o >>= 1) v += __shfl_xor(v, o);
    if ((tid & 63) == 0) wsum[tid >> 6] = v;
    __syncthreads();
    int off = wsum[0] + wsum[1] + wsum[2] + wsum[3];

    int i = blockIdx.x * 256 + tid;
    if (i < n) {
        int incl = row_ptr[i + 1] + off;
        row_ptr[i + 1] = incl;
        int c = cnt[i];
        int cp = (c + 3) & ~3;
        cursor[i] = incl - cp;
        dinv[i] = rsqrtf((float)c + 1.0f);
        int bin = min(cp >> 2, 255);
        atomicAdd(&hist[bin], 1);
        if (i == 0) row_ptr[0] = 0;
    }
}

// exclusive scan of 256 degree bins -> bin cursors
__global__ void bin_scan_kernel(const int* __restrict__ hist, int* __restrict__ bincur) {
    __shared__ int lds[256];
    const int tid = threadIdx.x;
    int h = hist[tid];
    lds[tid] = h;
    __syncthreads();
    for (int off = 1; off < 256; off <<= 1) {
        int t = (tid >= off) ? lds[tid - off] : 0;
        __syncthreads();
        lds[tid] += t;
        __syncthreads();
    }
    bincur[tid] = lds[tid] - h;    // exclusive
}

// scatter nodes into degree-sorted permutation
__global__ void perm_kernel(const int* __restrict__ cnt, int* __restrict__ bincur,
                            int* __restrict__ perm, int n) {
    int i = blockIdx.x * blockDim.x + threadIdx.x;
    if (i < n) {
        int cp = (cnt[i] + 3) & ~3;
        int bin = min(cp >> 2, 255);
        int pos = atomicAdd(&bincur[bin], 1);
        perm[pos] = i;
    }
}

// fill padded csr with the dummy node index N (zero feature row)
__global__ void fill_kernel(int* __restrict__ csr, int val, int total4) {
    int idx = blockIdx.x * blockDim.x + threadIdx.x;
    if (idx < total4) {
        int4 v = {val, val, val, val};
        ((int4*)csr)[idx] = v;
    }
}

__global__ void scatter_kernel(const int* __restrict__ src, const int* __restrict__ dst,
                               int* __restrict__ cursor, int* __restrict__ csr, int E) {
    int e4 = blockIdx.x * blockDim.x + threadIdx.x;
    if (e4 * 4 + 3 < E) {
        int4 s = ((const int4*)src)[e4];
        int4 d = ((const int4*)dst)[e4];
        csr[atomicAdd(&cursor[d.x], 1)] = s.x;
        csr[atomicAdd(&cursor[d.y], 1)] = s.y;
        csr[atomicAdd(&cursor[d.z], 1)] = s.z;
        csr[atomicAdd(&cursor[d.w], 1)] = s.w;
    } else {
        for (int e = e4 * 4; e < E; ++e)
            csr[atomicAdd(&cursor[dst[e]], 1)] = src[e];
    }
}

// ---------- prep: xh[j] = dinv[j] * x[j] as fp16 ----------
__global__ void prep_kernel(const float* __restrict__ x, const float* __restrict__ dinv,
                            __half* __restrict__ xh, int total4) {   // total4 = N*32
    int idx = blockIdx.x * blockDim.x + threadIdx.x;
    if (idx < total4) {
        float d = dinv[idx >> 5];
        float4 v = ((const float4*)x)[idx];
        union { uint2 u; __half2 h[2]; } r;
        r.h[0] = __floats2half2_rn(d * v.x, d * v.y);
        r.h[1] = __floats2half2_rn(d * v.z, d * v.w);
        ((uint2*)xh)[idx] = r.u;
    }
}

__global__ void zero_row_kernel(__half* __restrict__ m, int row) {
    ((uint4*)(m + (size_t)row * NFEAT))[threadIdx.x] = uint4{0, 0, 0, 0};  // 16 threads
}

// ---------- gather core (R6 structure: padded rows, batched tail) ----------
__device__ __forceinline__ void gather_row(float acc[8], const uint4* __restrict__ X,
                                           const int* __restrict__ csr,
                                           int ks, int ke, int sub, int q, int Nd) {
    int k = ks;
    int j0, j1, j2, j3;
    bool have = (k + 16 <= ke);
    if (have) {
        j0 = csr[k + sub]; j1 = csr[k + 4 + sub];
        j2 = csr[k + 8 + sub]; j3 = csr[k + 12 + sub];
    }
    while (have) {
        uint4 v0 = X[(size_t)j0 * RQ + q];
        uint4 v1 = X[(size_t)j1 * RQ + q];
        uint4 v2 = X[(size_t)j2 * RQ + q];
        uint4 v3 = X[(size_t)j3 * RQ + q];
        k += 16;
        have = (k + 16 <= ke);
        if (have) {
            j0 = csr[k + sub]; j1 = csr[k + 4 + sub];
            j2 = csr[k + 8 + sub]; j3 = csr[k + 12 + sub];
        }
        accum_h8(acc, v0); accum_h8(acc, v1);
        accum_h8(acc, v2); accum_h8(acc, v3);
    }
    int rem = (ke - k) >> 2;                      // 0..3, wave-uniform
    if (rem) {
        int t0 = csr[k + sub];
        int t1 = csr[k + 4 + sub];      // may overrun row (slack allocated) -> valid ids
        int t2 = csr[k + 8 + sub];
        if (rem < 2) t1 = Nd;
        if (rem < 3) t2 = Nd;
        uint4 v0 = X[(size_t)t0 * RQ + q];
        uint4 v1 = X[(size_t)t1 * RQ + q];
        uint4 v2 = X[(size_t)t2 * RQ + q];
        accum_h8(acc, v0); accum_h8(acc, v1); accum_h8(acc, v2);
    }
}

// ---------- generic hop: out_h[i] = fp16( scale_i * (sum_j in_h[j] + in_h[i]) ) ----------
// SQUARE=1: scale = dinv^2 (hop1: y1 = dinv^2*(sum xh + xh_i), xh pre-scaled by dinv)
// SQUARE=0: scale = dinv   (hop2: x2 = dinv*(sum y1 + y1_i))
template <int SQUARE>
__global__ __launch_bounds__(512) void hop_kernel(const __half* __restrict__ in_h,
                                                  const float* __restrict__ dinv,
                                                  const int* __restrict__ row_ptr,
                                                  const int* __restrict__ csr,
                                                  const int* __restrict__ perm,
                                                  __half* __restrict__ out_h, int N) {
    const int tid = threadIdx.x;
    const int w = tid >> 6, lane = tid & 63;
    const int idx = blockIdx.x * 8 + w;
    if (idx >= N) return;                         // wave-uniform
    const int i = perm[idx];                      // degree-balanced assignment
    const int sub = lane >> 4;
    const int q = lane & 15;
    const uint4* X = (const uint4*)in_h;

    float acc[8] = {0.f, 0.f, 0.f, 0.f, 0.f, 0.f, 0.f, 0.f};
    int ks = row_ptr[i], ke = row_ptr[i + 1];
    gather_row(acc, X, csr, ks, ke, sub, q, N);
    if (sub == 0) accum_h8(acc, X[(size_t)i * RQ + q]);   // self term

    #pragma unroll
    for (int t = 0; t < 8; ++t) {
        acc[t] += __shfl_xor(acc[t], 16);
        acc[t] += __shfl_xor(acc[t], 32);
    }

    if (sub == 0) {
        float di = dinv[i];
        float s = SQUARE ? di * di : di;
        union { uint4 u; __half2 h[4]; } r;
        #pragma unroll
        for (int t = 0; t < 4; ++t)
            r.h[t] = __floats2half2_rn(s * acc[2 * t], s * acc[2 * t + 1]);
        ((uint4*)out_h)[(size_t)i * RQ + q] = r.u;
    }
}

// ---------- classifier: logits = x2 @ W^T + b, log_softmax ----------
// W rows live in VGPRs (64 x half2 per lane; lane = class). x2 staged in LDS
// per 64-node tile; h reads are wave-broadcast (near-zero LDS bandwidth).
__global__ __launch_bounds__(512) void cls_kernel(const __half* __restrict__ x2h,
                                                  const float* __restrict__ W,
                                                  const float* __restrict__ b,
                                                  float* __restrict__ out, int N) {
    __shared__ __half Wl[NCLS * WSTR];            // 16.9 KB
    __shared__ __align__(16) __half HT[64][NFEAT]; // 16 KB node tile

    const int tid = threadIdx.x;
    const int w = tid >> 6, lane = tid & 63;

    // stage W (fp16) coalesced
    for (int e = tid; e < NCLS * NFEAT; e += 512) {
        int r = e >> 7, c = e & 127;
        Wl[r * WSTR + c] = __float2half(W[e]);
    }
    // stage x2 tile (nodes tile*64 .. +63), coalesced 16B
    const size_t base = (size_t)blockIdx.x * 64 * NFEAT;
    {
        const uint4* src = (const uint4*)(x2h + base);   // slack-allocated: safe overrun
        uint4* dst = (uint4*)&HT[0][0];
        dst[tid] = src[tid];
        dst[tid + 512] = src[tid + 512];
    }
    __syncthreads();

    // pull W row `lane` into registers: 32 x b64 = 64 half2
    unsigned int wreg[64];
    {
        const unsigned int* wr = (const unsigned int*)&Wl[lane * WSTR];
        #pragma unroll
        for (int t = 0; t < 32; ++t) {
            uint2 v = ((const uint2*)wr)[t];
            wreg[2 * t] = v.x; wreg[2 * t + 1] = v.y;
        }
    }
    const float breg = b[lane];

    // each wave classifies 8 nodes
    #pragma unroll 1
    for (int r = 0; r < 8; ++r) {
        int node = blockIdx.x * 64 + w * 8 + r;
        if (node >= N) break;
        const unsigned int* hrow = (const unsigned int*)&HT[w * 8 + r][0];
        float dot = breg;
        #pragma unroll
        for (int t = 0; t < 64; ++t)
            dot = dot2acc(hrow[t], wreg[t], dot);   // broadcast LDS read + v_dot2

        float m = dot;
        for (int o = 32; o > 0; o >>= 1) m = fmaxf(m, __shfl_xor(m, o));
        float ex = __expf(dot - m);
        float se = ex;
        for (int o = 32; o > 0; o >>= 1) se += __shfl_xor(se, o);
        out[(size_t)node * NCLS + lane] = dot - m - logf(se);
    }
}

// ---------- launch ----------

static inline size_t align256(size_t v) { return (v + 255) & ~(size_t)255; }

extern "C" void kernel_launch(void* const* d_in, const int* in_sizes, int n_in,
                              void* d_out, int out_size, void* d_ws, size_t ws_size,
                              hipStream_t stream) {
    const float* x  = (const float*)d_in[0];
    const int*   ei = (const int*)d_in[1];
    const float* W  = (const float*)d_in[2];
    const float* b  = (const float*)d_in[3];
    float* out = (float*)d_out;

    const int N = in_sizes[0] / NFEAT;   // 50000
    const int E = in_sizes[1] / 2;       // 800000
    const int* src = ei;
    const int* dst = ei + E;
    const int NB = (N + 255) / 256;

    const int CSR_CAP = E + 3 * N + 64;  // padded csr + read-overrun slack

    char* ws = (char*)d_ws;
    size_t o = 0;
    int*    cnt     = (int*)(ws + o);    o += align256((size_t)N * 4);
    float*  dinv    = (float*)(ws + o);  o += align256((size_t)N * 4);
    int*    row_ptr = (int*)(ws + o);    o += align256((size_t)(N + 1) * 4);
    int*    cursor  = (int*)(ws + o);    o += align256((size_t)N * 4);
    int*    bsums   = (int*)(ws + o);    o += align256(256 * 4);
    int*    hist    = (int*)(ws + o);    o += align256(256 * 4);
    int*    bincur  = (int*)(ws + o);    o += align256(256 * 4);
    int*    perm    = (int*)(ws + o);    o += align256((size_t)N * 4);
    int*    csr     = (int*)(ws + o);    o += align256((size_t)CSR_CAP * 4);
    __half* xh      = (__half*)(ws + o); o += align256((size_t)(N + 64) * NFEAT * 2); // reused as x2 (+tile slack)
    __half* y1h     = (__half*)(ws + o); o += align256((size_t)(N + 1) * NFEAT * 2);
    __half* x2h     = xh;                // xh dead after hop1; reuse for x2

    const int E4 = (E + 3) / 4;
    const int F4 = (CSR_CAP + 3) / 4;

    hipMemsetAsync(cnt, 0, (size_t)N * 4, stream);
    hipMemsetAsync(hist, 0, 256 * 4, stream);
    count_kernel<<<(E4 + 255) / 256, 256, 0, stream>>>(dst, cnt, E);
    scan_local<<<NB, 256, 0, stream>>>(cnt, row_ptr, bsums, N);
    scan_finalize<<<NB, 256, 0, stream>>>(cnt, bsums, row_ptr, cursor, dinv, hist, N);
    bin_scan_kernel<<<1, 256, 0, stream>>>(hist, bincur);
    perm_kernel<<<NB, 256, 0, stream>>>(cnt, bincur, perm, N);
    fill_kernel<<<(F4 + 255) / 256, 256, 0, stream>>>(csr, N, F4);
    scatter_kernel<<<(E4 + 255) / 256, 256, 0, stream>>>(src, dst, cursor, csr, E);
    prep_kernel<<<(N * 32 + 255) / 256, 256, 0, stream>>>(x, dinv, xh, N * 32);
    zero_row_kernel<<<1, 16, 0, stream>>>(xh, N);
    zero_row_kernel<<<1, 16, 0, stream>>>(y1h, N);
    hop_kernel<1><<<(N + 7) / 8, 512, 0, stream>>>(xh, dinv, row_ptr, csr, perm, y1h, N);
    hop_kernel<0><<<(N + 7) / 8, 512, 0, stream>>>(y1h, dinv, row_ptr, csr, perm, x2h, N);
    cls_kernel<<<(N + 63) / 64, 512, 0, stream>>>(x2h, W, b, out, N);
}

// Round 8
// 264.374 us; speedup vs baseline: 3.1726x; 3.1726x over previous
//
#include <hip/hip_runtime.h>
#include <hip/hip_bf16.h>
#include <hip/hip_fp16.h>
#include <math.h>

#define NFEAT 128
#define NCLS  64
#define RQ    16            // uint4 per fp16 row (128*2/16)
#define WSTR  132           // W LDS row stride in halves (264 B, b64-aligned)

// ---------- helpers ----------

__device__ __forceinline__ void accum_h8(float acc[8], uint4 v) {
    union { uint4 u; __half2 h[4]; } c; c.u = v;
    #pragma unroll
    for (int t = 0; t < 4; ++t) {
        float2 f = __half22float2(c.h[t]);
        acc[2 * t]     += f.x;
        acc[2 * t + 1] += f.y;
    }
}

typedef _Float16 h2v __attribute__((ext_vector_type(2)));

__device__ __forceinline__ float dot2acc(unsigned int hv, unsigned int wv, float c) {
#if __has_builtin(__builtin_amdgcn_fdot2)
    union { unsigned int u; h2v v; } a, bq; a.u = hv; bq.u = wv;
    return __builtin_amdgcn_fdot2(a.v, bq.v, c, false);
#else
    union { unsigned int u; __half2 h; } a, bq; a.u = hv; bq.u = wv;
    float2 fa = __half22float2(a.h), fb = __half22float2(bq.h);
    return fmaf(fa.x, fb.x, fmaf(fa.y, fb.y, c));
#endif
}

// ---------- graph build ----------

__global__ void count_kernel(const int* __restrict__ dst, int* __restrict__ cnt, int E) {
    int e4 = blockIdx.x * blockDim.x + threadIdx.x;     // 4 edges per thread
    if (e4 * 4 + 3 < E) {
        int4 d = ((const int4*)dst)[e4];
        atomicAdd(&cnt[d.x], 1); atomicAdd(&cnt[d.y], 1);
        atomicAdd(&cnt[d.z], 1); atomicAdd(&cnt[d.w], 1);
    } else {
        for (int e = e4 * 4; e < E; ++e) atomicAdd(&cnt[dst[e]], 1);
    }
}

// scan over PADDED counts (round up to multiple of 4)
__global__ void scan_local(const int* __restrict__ cnt, int* __restrict__ row_ptr,
                           int* __restrict__ bsums, int n) {
    __shared__ int lds[256];
    const int tid = threadIdx.x;
    int i = blockIdx.x * 256 + tid;
    int v = (i < n) ? ((cnt[i] + 3) & ~3) : 0;
    lds[tid] = v;
    __syncthreads();
    for (int off = 1; off < 256; off <<= 1) {
        int t = (tid >= off) ? lds[tid - off] : 0;
        __syncthreads();
        lds[tid] += t;
        __syncthreads();
    }
    if (i < n) row_ptr[i + 1] = lds[tid];
    if (tid == 255) bsums[blockIdx.x] = lds[255];
}

// finalize with fused block-offset reduction (nb <= 256 blocks); NO atomics
__global__ void scan_finalize(const int* __restrict__ cnt, const int* __restrict__ bsums,
                              int* __restrict__ row_ptr, int* __restrict__ cursor,
                              float* __restrict__ dinv, int n) {
    __shared__ int wsum[4];
    const int tid = threadIdx.x;
    int v = (tid < blockIdx.x) ? bsums[tid] : 0;
    for (int o = 32; o > 0; o >>= 1) v += __shfl_xor(v, o);
    if ((tid & 63) == 0) wsum[tid >> 6] = v;
    __syncthreads();
    int off = wsum[0] + wsum[1] + wsum[2] + wsum[3];

    int i = blockIdx.x * 256 + tid;
    if (i < n) {
        int incl = row_ptr[i + 1] + off;
        row_ptr[i + 1] = incl;
        int c = cnt[i];
        int cp = (c + 3) & ~3;
        cursor[i] = incl - cp;                     // row start; pads land at row end
        dinv[i] = rsqrtf((float)c + 1.0f);         // +1 self-loop (true degree)
        if (i == 0) row_ptr[0] = 0;
    }
}

// fill padded csr with the dummy node index N (zero feature row)
__global__ void fill_kernel(int* __restrict__ csr, int val, int total4) {
    int idx = blockIdx.x * blockDim.x + threadIdx.x;
    if (idx < total4) {
        int4 v = {val, val, val, val};
        ((int4*)csr)[idx] = v;
    }
}

__global__ void scatter_kernel(const int* __restrict__ src, const int* __restrict__ dst,
                               int* __restrict__ cursor, int* __restrict__ csr, int E) {
    int e4 = blockIdx.x * blockDim.x + threadIdx.x;
    if (e4 * 4 + 3 < E) {
        int4 s = ((const int4*)src)[e4];
        int4 d = ((const int4*)dst)[e4];
        csr[atomicAdd(&cursor[d.x], 1)] = s.x;
        csr[atomicAdd(&cursor[d.y], 1)] = s.y;
        csr[atomicAdd(&cursor[d.z], 1)] = s.z;
        csr[atomicAdd(&cursor[d.w], 1)] = s.w;
    } else {
        for (int e = e4 * 4; e < E; ++e)
            csr[atomicAdd(&cursor[dst[e]], 1)] = src[e];
    }
}

// ---------- prep: xh[j] = dinv[j] * x[j] as fp16 ----------
__global__ void prep_kernel(const float* __restrict__ x, const float* __restrict__ dinv,
                            __half* __restrict__ xh, int total4) {   // total4 = N*32
    int idx = blockIdx.x * blockDim.x + threadIdx.x;
    if (idx < total4) {
        float d = dinv[idx >> 5];
        float4 v = ((const float4*)x)[idx];
        union { uint2 u; __half2 h[2]; } r;
        r.h[0] = __floats2half2_rn(d * v.x, d * v.y);
        r.h[1] = __floats2half2_rn(d * v.z, d * v.w);
        ((uint2*)xh)[idx] = r.u;
    }
}

// zero dummy row N of both fp16 matrices in one launch (32 threads)
__global__ void zero_rows_kernel(__half* __restrict__ a, __half* __restrict__ bm, int row) {
    int t = threadIdx.x;
    if (t < 16) ((uint4*)(a  + (size_t)row * NFEAT))[t]      = uint4{0, 0, 0, 0};
    else        ((uint4*)(bm + (size_t)row * NFEAT))[t - 16] = uint4{0, 0, 0, 0};
}

// ---------- gather core (R6 structure: padded rows, batched tail) ----------
__device__ __forceinline__ void gather_row(float acc[8], const uint4* __restrict__ X,
                                           const int* __restrict__ csr,
                                           int ks, int ke, int sub, int q, int Nd) {
    int k = ks;
    int j0, j1, j2, j3;
    bool have = (k + 16 <= ke);
    if (have) {
        j0 = csr[k + sub]; j1 = csr[k + 4 + sub];
        j2 = csr[k + 8 + sub]; j3 = csr[k + 12 + sub];
    }
    while (have) {
        uint4 v0 = X[(size_t)j0 * RQ + q];
        uint4 v1 = X[(size_t)j1 * RQ + q];
        uint4 v2 = X[(size_t)j2 * RQ + q];
        uint4 v3 = X[(size_t)j3 * RQ + q];
        k += 16;
        have = (k + 16 <= ke);
        if (have) {                               // prefetch next indices while v* in flight
            j0 = csr[k + sub]; j1 = csr[k + 4 + sub];
            j2 = csr[k + 8 + sub]; j3 = csr[k + 12 + sub];
        }
        accum_h8(acc, v0); accum_h8(acc, v1);
        accum_h8(acc, v2); accum_h8(acc, v3);
    }
    int rem = (ke - k) >> 2;                      // 0..3, wave-uniform
    if (rem) {
        int t0 = csr[k + sub];
        int t1 = csr[k + 4 + sub];      // may overrun row (slack allocated) -> valid ids
        int t2 = csr[k + 8 + sub];
        if (rem < 2) t1 = Nd;
        if (rem < 3) t2 = Nd;
        uint4 v0 = X[(size_t)t0 * RQ + q];
        uint4 v1 = X[(size_t)t1 * RQ + q];
        uint4 v2 = X[(size_t)t2 * RQ + q];
        accum_h8(acc, v0); accum_h8(acc, v1); accum_h8(acc, v2);
    }
}

// ---------- generic hop: out_h[i] = fp16( scale_i * (sum_j in_h[j] + in_h[i]) ) ----------
// SQUARE=1: scale = dinv^2 (hop1); SQUARE=0: scale = dinv (hop2)
template <int SQUARE>
__global__ __launch_bounds__(512) void hop_kernel(const __half* __restrict__ in_h,
                                                  const float* __restrict__ dinv,
                                                  const int* __restrict__ row_ptr,
                                                  const int* __restrict__ csr,
                                                  __half* __restrict__ out_h, int N) {
    const int tid = threadIdx.x;
    const int w = tid >> 6, lane = tid & 63;
    const int i = blockIdx.x * 8 + w;
    if (i >= N) return;                           // wave-uniform; no barriers
    const int sub = lane >> 4;
    const int q = lane & 15;
    const uint4* X = (const uint4*)in_h;

    float acc[8] = {0.f, 0.f, 0.f, 0.f, 0.f, 0.f, 0.f, 0.f};
    int ks = row_ptr[i], ke = row_ptr[i + 1];
    gather_row(acc, X, csr, ks, ke, sub, q, N);
    if (sub == 0) accum_h8(acc, X[(size_t)i * RQ + q]);   // self term

    #pragma unroll
    for (int t = 0; t < 8; ++t) {
        acc[t] += __shfl_xor(acc[t], 16);
        acc[t] += __shfl_xor(acc[t], 32);
    }

    if (sub == 0) {
        float di = dinv[i];
        float s = SQUARE ? di * di : di;
        union { uint4 u; __half2 h[4]; } r;
        #pragma unroll
        for (int t = 0; t < 4; ++t)
            r.h[t] = __floats2half2_rn(s * acc[2 * t], s * acc[2 * t + 1]);
        ((uint4*)out_h)[(size_t)i * RQ + q] = r.u;
    }
}

// ---------- classifier: logits = x2 @ W^T + b, log_softmax ----------
// W row per lane (lane = class) in 64 VGPRs, loaded once per block; x2 staged
// in LDS per 64-node tile; h-reads are wave-broadcast (near-zero LDS BW).
__global__ __launch_bounds__(512) void cls_kernel(const __half* __restrict__ x2h,
                                                  const float* __restrict__ W,
                                                  const float* __restrict__ b,
                                                  float* __restrict__ out, int N) {
    __shared__ __half Wl[NCLS * WSTR];             // 16.9 KB
    __shared__ __align__(16) __half HT[64][NFEAT]; // 16 KB node tile

    const int tid = threadIdx.x;
    const int w = tid >> 6, lane = tid & 63;

    // stage W (fp16) coalesced
    for (int e = tid; e < NCLS * NFEAT; e += 512) {
        int r = e >> 7, c = e & 127;
        Wl[r * WSTR + c] = __float2half(W[e]);
    }
    // stage x2 tile (nodes tile*64 .. +63), coalesced 16B
    const size_t base = (size_t)blockIdx.x * 64 * NFEAT;
    {
        const uint4* src = (const uint4*)(x2h + base);   // slack-allocated: safe overrun
        uint4* dst = (uint4*)&HT[0][0];
        dst[tid] = src[tid];
        dst[tid + 512] = src[tid + 512];
    }
    __syncthreads();

    // pull W row `lane` into registers: 64 half2
    unsigned int wreg[64];
    {
        const uint2* wr = (const uint2*)&Wl[lane * WSTR];
        #pragma unroll
        for (int t = 0; t < 32; ++t) {
            uint2 v = wr[t];
            wreg[2 * t] = v.x; wreg[2 * t + 1] = v.y;
        }
    }
    const float breg = b[lane];

    // each wave classifies 8 nodes
    #pragma unroll 1
    for (int r = 0; r < 8; ++r) {
        int node = blockIdx.x * 64 + w * 8 + r;
        if (node >= N) break;
        const unsigned int* hrow = (const unsigned int*)&HT[w * 8 + r][0];
        float dot = breg;
        #pragma unroll
        for (int t = 0; t < 64; ++t)
            dot = dot2acc(hrow[t], wreg[t], dot);   // broadcast LDS read + v_dot2

        float m = dot;
        for (int o = 32; o > 0; o >>= 1) m = fmaxf(m, __shfl_xor(m, o));
        float ex = __expf(dot - m);
        float se = ex;
        for (int o = 32; o > 0; o >>= 1) se += __shfl_xor(se, o);
        out[(size_t)node * NCLS + lane] = dot - m - logf(se);
    }
}

// ---------- launch ----------

static inline size_t align256(size_t v) { return (v + 255) & ~(size_t)255; }

extern "C" void kernel_launch(void* const* d_in, const int* in_sizes, int n_in,
                              void* d_out, int out_size, void* d_ws, size_t ws_size,
                              hipStream_t stream) {
    const float* x  = (const float*)d_in[0];
    const int*   ei = (const int*)d_in[1];
    const float* W  = (const float*)d_in[2];
    const float* b  = (const float*)d_in[3];
    float* out = (float*)d_out;

    const int N = in_sizes[0] / NFEAT;   // 50000
    const int E = in_sizes[1] / 2;       // 800000
    const int* src = ei;
    const int* dst = ei + E;
    const int NB = (N + 255) / 256;

    const int CSR_CAP = E + 3 * N + 64;  // padded csr + read-overrun slack

    char* ws = (char*)d_ws;
    size_t o = 0;
    int*    cnt     = (int*)(ws + o);    o += align256((size_t)N * 4);
    float*  dinv    = (float*)(ws + o);  o += align256((size_t)N * 4);
    int*    row_ptr = (int*)(ws + o);    o += align256((size_t)(N + 1) * 4);
    int*    cursor  = (int*)(ws + o);    o += align256((size_t)N * 4);
    int*    bsums   = (int*)(ws + o);    o += align256(256 * 4);
    int*    csr     = (int*)(ws + o);    o += align256((size_t)CSR_CAP * 4);
    __half* xh      = (__half*)(ws + o); o += align256((size_t)(N + 64) * NFEAT * 2); // reused as x2 (+tile slack)
    __half* y1h     = (__half*)(ws + o); o += align256((size_t)(N + 1) * NFEAT * 2);
    __half* x2h     = xh;                // xh dead after hop1; reuse for x2

    const int E4 = (E + 3) / 4;
    const int F4 = (CSR_CAP + 3) / 4;

    hipMemsetAsync(cnt, 0, (size_t)N * 4, stream);
    count_kernel<<<(E4 + 255) / 256, 256, 0, stream>>>(dst, cnt, E);
    scan_local<<<NB, 256, 0, stream>>>(cnt, row_ptr, bsums, N);
    scan_finalize<<<NB, 256, 0, stream>>>(cnt, bsums, row_ptr, cursor, dinv, N);
    fill_kernel<<<(F4 + 255) / 256, 256, 0, stream>>>(csr, N, F4);
    scatter_kernel<<<(E4 + 255) / 256, 256, 0, stream>>>(src, dst, cursor, csr, E);
    prep_kernel<<<(N * 32 + 255) / 256, 256, 0, stream>>>(x, dinv, xh, N * 32);
    zero_rows_kernel<<<1, 32, 0, stream>>>(xh, y1h, N);
    hop_kernel<1><<<(N + 7) / 8, 512, 0, stream>>>(xh, dinv, row_ptr, csr, y1h, N);
    hop_kernel<0><<<(N + 7) / 8, 512, 0, stream>>>(y1h, dinv, row_ptr, csr, x2h, N);
    cls_kernel<<<(N + 63) / 64, 512, 0, stream>>>(x2h, W, b, out, N);
}

// Round 9
// 243.437 us; speedup vs baseline: 3.4454x; 1.0860x over previous
//
#include <hip/hip_runtime.h>
#include <hip/hip_bf16.h>
#include <hip/hip_fp16.h>
#include <math.h>

#define NFEAT 128
#define NCLS  64
#define RQ    16            // uint4 per fp16 row (128*2/16)
#define WSTR  132           // W LDS row stride in halves
#define NBLK  256           // fixed grid for hist/scatter replay passes

// ---------- helpers ----------

__device__ __forceinline__ void accum_h8(float acc[8], uint4 v) {
    union { uint4 u; __half2 h[4]; } c; c.u = v;
    #pragma unroll
    for (int t = 0; t < 4; ++t) {
        float2 f = __half22float2(c.h[t]);
        acc[2 * t]     += f.x;
        acc[2 * t + 1] += f.y;
    }
}

typedef _Float16 h2v __attribute__((ext_vector_type(2)));

__device__ __forceinline__ float dot2acc(unsigned int hv, unsigned int wv, float c) {
#if __has_builtin(__builtin_amdgcn_fdot2)
    union { unsigned int u; h2v v; } a, bq; a.u = hv; bq.u = wv;
    return __builtin_amdgcn_fdot2(a.v, bq.v, c, false);
#else
    union { unsigned int u; __half2 h; } a, bq; a.u = hv; bq.u = wv;
    float2 fa = __half22float2(a.h), fb = __half22float2(bq.h);
    return fmaf(fa.x, fb.x, fmaf(fa.y, fb.y, c));
#endif
}

// ---------- build pass 1: per-node count + coarse bucket histogram ----------
// bucket = dst >> 8 (196 buckets for N=50k). h[block][bucket], stride 256.
__global__ __launch_bounds__(256) void histcount_kernel(const int* __restrict__ dst,
                                                        int* __restrict__ cnt,
                                                        int* __restrict__ h,
                                                        int E4, int E, int nbuck) {
    __shared__ int lh[256];
    const int tid = threadIdx.x;
    lh[tid] = 0;
    __syncthreads();
    for (int idx = blockIdx.x * 256 + tid; idx < E4; idx += NBLK * 256) {
        int base = idx * 4;
        if (base + 3 < E) {
            int4 d = ((const int4*)dst)[idx];
            atomicAdd(&cnt[d.x], 1); atomicAdd(&lh[d.x >> 8], 1);
            atomicAdd(&cnt[d.y], 1); atomicAdd(&lh[d.y >> 8], 1);
            atomicAdd(&cnt[d.z], 1); atomicAdd(&lh[d.z >> 8], 1);
            atomicAdd(&cnt[d.w], 1); atomicAdd(&lh[d.w >> 8], 1);
        } else {
            for (int e = base; e < E; ++e) {
                int d = dst[e];
                atomicAdd(&cnt[d], 1); atomicAdd(&lh[d >> 8], 1);
            }
        }
    }
    __syncthreads();
    if (tid < nbuck) h[blockIdx.x * 256 + tid] = lh[tid];
}

// pass 2a: per bucket, exclusive scan over its 256 block-counts (in place) + total
__global__ __launch_bounds__(256) void bucket_colscan_kernel(int* __restrict__ h,
                                                             int* __restrict__ btot) {
    __shared__ int lds[256];
    const int tid = threadIdx.x;
    const int B = blockIdx.x;
    int v = h[tid * 256 + B];
    lds[tid] = v;
    __syncthreads();
    for (int off = 1; off < 256; off <<= 1) {
        int t = (tid >= off) ? lds[tid - off] : 0;
        __syncthreads();
        lds[tid] += t;
        __syncthreads();
    }
    h[tid * 256 + B] = lds[tid] - v;               // exclusive within bucket
    if (tid == 255) btot[B] = lds[255];
}

// pass 2b: exclusive scan of bucket totals -> bbase[0..nbuck], bbase[nbuck]=E
__global__ __launch_bounds__(256) void bucket_scan_kernel(const int* __restrict__ btot,
                                                          int* __restrict__ bbase, int nbuck) {
    __shared__ int lds[256];
    const int tid = threadIdx.x;
    int v = (tid < nbuck) ? btot[tid] : 0;
    lds[tid] = v;
    __syncthreads();
    for (int off = 1; off < 256; off <<= 1) {
        int t = (tid >= off) ? lds[tid - off] : 0;
        __syncthreads();
        lds[tid] += t;
        __syncthreads();
    }
    if (tid < nbuck) bbase[tid] = lds[tid] - v;
    if (tid == nbuck - 1) bbase[nbuck] = lds[tid];
}

// pass 3: replay edges (same per-block order as K1), write pairs into buckets
__global__ __launch_bounds__(256) void bucket_scatter_kernel(const int* __restrict__ src,
                                                             const int* __restrict__ dst,
                                                             const int* __restrict__ h,
                                                             const int* __restrict__ bbase,
                                                             int* __restrict__ bsrc,
                                                             int* __restrict__ bdst,
                                                             int E4, int E, int nbuck) {
    __shared__ int cur[256];
    const int tid = threadIdx.x;
    if (tid < nbuck) cur[tid] = bbase[tid] + h[blockIdx.x * 256 + tid];
    __syncthreads();
    for (int idx = blockIdx.x * 256 + tid; idx < E4; idx += NBLK * 256) {
        int base = idx * 4;
        if (base + 3 < E) {
            int4 s = ((const int4*)src)[idx];
            int4 d = ((const int4*)dst)[idx];
            int p;
            p = atomicAdd(&cur[d.x >> 8], 1); bsrc[p] = s.x; bdst[p] = d.x;
            p = atomicAdd(&cur[d.y >> 8], 1); bsrc[p] = s.y; bdst[p] = d.y;
            p = atomicAdd(&cur[d.z >> 8], 1); bsrc[p] = s.z; bdst[p] = d.z;
            p = atomicAdd(&cur[d.w >> 8], 1); bsrc[p] = s.w; bdst[p] = d.w;
        } else {
            for (int e = base; e < E; ++e) {
                int p = atomicAdd(&cur[dst[e] >> 8], 1);
                bsrc[p] = src[e]; bdst[p] = dst[e];
            }
        }
    }
}

// pass 4: one workgroup drains one bucket; csr writes confined to one ~60KB
// slice from one CU/XCD -> no cross-XCD dirty-line amplification.
__global__ __launch_bounds__(256) void drain_kernel(const int* __restrict__ bsrc,
                                                    const int* __restrict__ bdst,
                                                    const int* __restrict__ bbase,
                                                    int* __restrict__ cursor,
                                                    int* __restrict__ csr) {
    const int B = blockIdx.x;
    const int s0 = bbase[B], s1 = bbase[B + 1];
    for (int e = s0 + threadIdx.x; e < s1; e += 256) {
        int sj = bsrc[e], dj = bdst[e];
        int pos = atomicAdd(&cursor[dj], 1);
        csr[pos] = sj;
    }
}

// ---------- scans over padded per-node counts (row_ptr / cursor / dinv) ----------

__global__ void scan_local(const int* __restrict__ cnt, int* __restrict__ row_ptr,
                           int* __restrict__ bsums, int n) {
    __shared__ int lds[256];
    const int tid = threadIdx.x;
    int i = blockIdx.x * 256 + tid;
    int v = (i < n) ? ((cnt[i] + 3) & ~3) : 0;
    lds[tid] = v;
    __syncthreads();
    for (int off = 1; off < 256; off <<= 1) {
        int t = (tid >= off) ? lds[tid - off] : 0;
        __syncthreads();
        lds[tid] += t;
        __syncthreads();
    }
    if (i < n) row_ptr[i + 1] = lds[tid];
    if (tid == 255) bsums[blockIdx.x] = lds[255];
}

__global__ void scan_finalize(const int* __restrict__ cnt, const int* __restrict__ bsums,
                              int* __restrict__ row_ptr, int* __restrict__ cursor,
                              float* __restrict__ dinv, int n) {
    __shared__ int wsum[4];
    const int tid = threadIdx.x;
    int v = (tid < blockIdx.x) ? bsums[tid] : 0;
    for (int o = 32; o > 0; o >>= 1) v += __shfl_xor(v, o);
    if ((tid & 63) == 0) wsum[tid >> 6] = v;
    __syncthreads();
    int off = wsum[0] + wsum[1] + wsum[2] + wsum[3];

    int i = blockIdx.x * 256 + tid;
    if (i < n) {
        int incl = row_ptr[i + 1] + off;
        row_ptr[i + 1] = incl;
        int c = cnt[i];
        int cp = (c + 3) & ~3;
        cursor[i] = incl - cp;                     // row start; pads land at row end
        dinv[i] = rsqrtf((float)c + 1.0f);         // +1 self-loop
        if (i == 0) row_ptr[0] = 0;
    }
}

// fill padded csr with the dummy node index N (zero feature row)
__global__ void fill_kernel(int* __restrict__ csr, int val, int total4) {
    int idx = blockIdx.x * blockDim.x + threadIdx.x;
    if (idx < total4) {
        int4 v = {val, val, val, val};
        ((int4*)csr)[idx] = v;
    }
}

// ---------- prep: xh[j] = dinv[j]*x[j] fp16; also zeroes dummy row N of xh & y1h ----------
__global__ void prep_kernel(const float* __restrict__ x, const float* __restrict__ dinv,
                            __half* __restrict__ xh, __half* __restrict__ y1h, int N) {
    int idx = blockIdx.x * blockDim.x + threadIdx.x;
    int total = N * 32;
    if (idx < total) {
        float d = dinv[idx >> 5];
        float4 v = ((const float4*)x)[idx];
        union { uint2 u; __half2 h[2]; } r;
        r.h[0] = __floats2half2_rn(d * v.x, d * v.y);
        r.h[1] = __floats2half2_rn(d * v.z, d * v.w);
        ((uint2*)xh)[idx] = r.u;
    } else if (idx < total + 32) {
        ((uint2*)xh)[idx]  = uint2{0, 0};
        ((uint2*)y1h)[idx] = uint2{0, 0};
    }
}

// ---------- gather core (padded rows, batched tail) ----------
__device__ __forceinline__ void gather_row(float acc[8], const uint4* __restrict__ X,
                                           const int* __restrict__ csr,
                                           int ks, int ke, int sub, int q, int Nd) {
    int k = ks;
    int j0, j1, j2, j3;
    bool have = (k + 16 <= ke);
    if (have) {
        j0 = csr[k + sub]; j1 = csr[k + 4 + sub];
        j2 = csr[k + 8 + sub]; j3 = csr[k + 12 + sub];
    }
    while (have) {
        uint4 v0 = X[(size_t)j0 * RQ + q];
        uint4 v1 = X[(size_t)j1 * RQ + q];
        uint4 v2 = X[(size_t)j2 * RQ + q];
        uint4 v3 = X[(size_t)j3 * RQ + q];
        k += 16;
        have = (k + 16 <= ke);
        if (have) {
            j0 = csr[k + sub]; j1 = csr[k + 4 + sub];
            j2 = csr[k + 8 + sub]; j3 = csr[k + 12 + sub];
        }
        accum_h8(acc, v0); accum_h8(acc, v1);
        accum_h8(acc, v2); accum_h8(acc, v3);
    }
    int rem = (ke - k) >> 2;                      // 0..3, wave-uniform
    if (rem) {
        int t0 = csr[k + sub];
        int t1 = csr[k + 4 + sub];      // may overrun row (slack allocated) -> valid ids
        int t2 = csr[k + 8 + sub];
        if (rem < 2) t1 = Nd;
        if (rem < 3) t2 = Nd;
        uint4 v0 = X[(size_t)t0 * RQ + q];
        uint4 v1 = X[(size_t)t1 * RQ + q];
        uint4 v2 = X[(size_t)t2 * RQ + q];
        accum_h8(acc, v0); accum_h8(acc, v1); accum_h8(acc, v2);
    }
}

// ---------- generic hop (256-thread blocks: finer retirement granularity) ----------
template <int SQUARE>
__global__ __launch_bounds__(256) void hop_kernel(const __half* __restrict__ in_h,
                                                  const float* __restrict__ dinv,
                                                  const int* __restrict__ row_ptr,
                                                  const int* __restrict__ csr,
                                                  __half* __restrict__ out_h, int N) {
    const int tid = threadIdx.x;
    const int w = tid >> 6, lane = tid & 63;
    const int i = blockIdx.x * 4 + w;
    if (i >= N) return;                           // wave-uniform; no barriers
    const int sub = lane >> 4;
    const int q = lane & 15;
    const uint4* X = (const uint4*)in_h;

    float acc[8] = {0.f, 0.f, 0.f, 0.f, 0.f, 0.f, 0.f, 0.f};
    int ks = row_ptr[i], ke = row_ptr[i + 1];
    gather_row(acc, X, csr, ks, ke, sub, q, N);
    if (sub == 0) accum_h8(acc, X[(size_t)i * RQ + q]);   // self term

    #pragma unroll
    for (int t = 0; t < 8; ++t) {
        acc[t] += __shfl_xor(acc[t], 16);
        acc[t] += __shfl_xor(acc[t], 32);
    }

    if (sub == 0) {
        float di = dinv[i];
        float s = SQUARE ? di * di : di;
        union { uint4 u; __half2 h[4]; } r;
        #pragma unroll
        for (int t = 0; t < 4; ++t)
            r.h[t] = __floats2half2_rn(s * acc[2 * t], s * acc[2 * t + 1]);
        ((uint4*)out_h)[(size_t)i * RQ + q] = r.u;
    }
}

// ---------- classifier: logits = x2 @ W^T + b, log_softmax ----------
__global__ __launch_bounds__(512) void cls_kernel(const __half* __restrict__ x2h,
                                                  const float* __restrict__ W,
                                                  const float* __restrict__ b,
                                                  float* __restrict__ out, int N) {
    __shared__ __half Wl[NCLS * WSTR];
    __shared__ __align__(16) __half HT[64][NFEAT];

    const int tid = threadIdx.x;
    const int w = tid >> 6, lane = tid & 63;

    for (int e = tid; e < NCLS * NFEAT; e += 512) {
        int r = e >> 7, c = e & 127;
        Wl[r * WSTR + c] = __float2half(W[e]);
    }
    const size_t base = (size_t)blockIdx.x * 64 * NFEAT;
    {
        const uint4* src = (const uint4*)(x2h + base);   // slack-allocated: safe overrun
        uint4* dst = (uint4*)&HT[0][0];
        dst[tid] = src[tid];
        dst[tid + 512] = src[tid + 512];
    }
    __syncthreads();

    unsigned int wreg[64];
    {
        const uint2* wr = (const uint2*)&Wl[lane * WSTR];
        #pragma unroll
        for (int t = 0; t < 32; ++t) {
            uint2 v = wr[t];
            wreg[2 * t] = v.x; wreg[2 * t + 1] = v.y;
        }
    }
    const float breg = b[lane];

    #pragma unroll 1
    for (int r = 0; r < 8; ++r) {
        int node = blockIdx.x * 64 + w * 8 + r;
        if (node >= N) break;
        const unsigned int* hrow = (const unsigned int*)&HT[w * 8 + r][0];
        float dot = breg;
        #pragma unroll
        for (int t = 0; t < 64; ++t)
            dot = dot2acc(hrow[t], wreg[t], dot);

        float m = dot;
        for (int o = 32; o > 0; o >>= 1) m = fmaxf(m, __shfl_xor(m, o));
        float ex = __expf(dot - m);
        float se = ex;
        for (int o = 32; o > 0; o >>= 1) se += __shfl_xor(se, o);
        out[(size_t)node * NCLS + lane] = dot - m - logf(se);
    }
}

// ---------- launch ----------

static inline size_t align256(size_t v) { return (v + 255) & ~(size_t)255; }

extern "C" void kernel_launch(void* const* d_in, const int* in_sizes, int n_in,
                              void* d_out, int out_size, void* d_ws, size_t ws_size,
                              hipStream_t stream) {
    const float* x  = (const float*)d_in[0];
    const int*   ei = (const int*)d_in[1];
    const float* W  = (const float*)d_in[2];
    const float* b  = (const float*)d_in[3];
    float* out = (float*)d_out;

    const int N = in_sizes[0] / NFEAT;   // 50000
    const int E = in_sizes[1] / 2;       // 800000
    const int* src = ei;
    const int* dst = ei + E;
    const int NB = (N + 255) / 256;      // 196 (also = bucket count, dst>>8)
    const int NBUCK = NB;

    const int CSR_CAP = E + 3 * N + 64;  // padded csr + read-overrun slack

    char* ws = (char*)d_ws;
    size_t o = 0;
    int*    cnt     = (int*)(ws + o);    o += align256((size_t)N * 4);
    float*  dinv    = (float*)(ws + o);  o += align256((size_t)N * 4);
    int*    row_ptr = (int*)(ws + o);    o += align256((size_t)(N + 1) * 4);
    int*    cursor  = (int*)(ws + o);    o += align256((size_t)N * 4);
    int*    bsums   = (int*)(ws + o);    o += align256(256 * 4);
    int*    h       = (int*)(ws + o);    o += align256((size_t)NBLK * 256 * 4);
    int*    btot    = (int*)(ws + o);    o += align256(256 * 4);
    int*    bbase   = (int*)(ws + o);    o += align256(257 * 4);
    int*    bsrc    = (int*)(ws + o);    o += align256((size_t)E * 4);
    int*    bdst    = (int*)(ws + o);    o += align256((size_t)E * 4);
    int*    csr     = (int*)(ws + o);    o += align256((size_t)CSR_CAP * 4);
    __half* xh      = (__half*)(ws + o); o += align256((size_t)(N + 64) * NFEAT * 2);
    __half* y1h     = (__half*)(ws + o); o += align256((size_t)(N + 1) * NFEAT * 2);
    __half* x2h     = xh;                // xh dead after hop1; reuse for x2

    const int E4 = (E + 3) / 4;
    const int F4 = (CSR_CAP + 3) / 4;

    hipMemsetAsync(cnt, 0, (size_t)N * 4, stream);
    histcount_kernel<<<NBLK, 256, 0, stream>>>(dst, cnt, h, E4, E, NBUCK);
    scan_local<<<NB, 256, 0, stream>>>(cnt, row_ptr, bsums, N);
    scan_finalize<<<NB, 256, 0, stream>>>(cnt, bsums, row_ptr, cursor, dinv, N);
    bucket_colscan_kernel<<<NBUCK, 256, 0, stream>>>(h, btot);
    bucket_scan_kernel<<<1, 256, 0, stream>>>(btot, bbase, NBUCK);
    bucket_scatter_kernel<<<NBLK, 256, 0, stream>>>(src, dst, h, bbase, bsrc, bdst, E4, E, NBUCK);
    fill_kernel<<<(F4 + 255) / 256, 256, 0, stream>>>(csr, N, F4);
    drain_kernel<<<NBUCK, 256, 0, stream>>>(bsrc, bdst, bbase, cursor, csr);
    prep_kernel<<<(N * 32 + 32 + 255) / 256, 256, 0, stream>>>(x, dinv, xh, y1h, N);
    hop_kernel<1><<<(N + 3) / 4, 256, 0, stream>>>(xh, dinv, row_ptr, csr, y1h, N);
    hop_kernel<0><<<(N + 3) / 4, 256, 0, stream>>>(y1h, dinv, row_ptr, csr, x2h, N);
    cls_kernel<<<(N + 63) / 64, 512, 0, stream>>>(x2h, W, b, out, N);
}